// Round 1
// baseline (206.121 us; speedup 1.0000x reference)
//
#include <hip/hip_runtime.h>
#include <hip/hip_bf16.h>
#include <math.h>

// out[b, :] = z[b, :] @ W[c_b*12288 : (c_b+1)*12288, :]^T + bias[c_b block]
//   z: (512,128) f32, W: (196608,128) f32, bias: (196608,), out: (512,12288) f32
//   c_b = mod(floor(|np.sum_f32_pairwise(z[b])| * 1000), 16)   (numpy-exact order)
//
// R5 theory: 68us main kernel was latency-bound (VALU 23%, HBM 20%) because
// z loads (L1-hit) and W prefetch (HBM, ~900cy) shared vmcnt -> every z wait
// drained the W stream. Fix: stage z tile (33KB) in LDS once per block; z
// reads become ds_read_b128 broadcasts on lgkmcnt, decoupled from W's vmcnt.
// Plus: n-adaptive NV in {1,2,3} accs (mean n=32 -> skip 1/3 of padded FMAs),
// lists in LDS for the epilogue, float4 hash loads (numpy order preserved).

#define N_LINEARS 16
#define ZD 128
#define BATCH 512
#define BLOCK_OUT 12288
#define STILE 48                  // one W pass for n<=48 (Binom mean 32, sd 5.5)
#define SLOTS 64
#define ZROWS (ZD + 1)            // pad row: steady-state k+1 prefetch at k=127
#define TJ 256

typedef float vf16 __attribute__((ext_vector_type(16)));
typedef vf16 vf16u __attribute__((aligned(16)));   // 16B-aligned vector loads

// ws layout: [0,64) counts | [64, 64+32768) lists | [36864, +2048) bp | zgT @65536
#define LISTS_OFF 16
#define BP_OFF (36864 / 4)
#define ZG_OFF_BYTES 65536

// ---------------- Kernel A1: hash (1 block, LDS atomics) ----------------
__global__ __launch_bounds__(512) void hash_kernel(
    const float* __restrict__ z, int* __restrict__ counts,
    int* __restrict__ lists, int* __restrict__ bp) {
  __shared__ int cnt[N_LINEARS];
  const int b = threadIdx.x;
  if (b < N_LINEARS) cnt[b] = 0;
  __syncthreads();

  // numpy pairwise_sum (n=128 <= PW_BLOCKSIZE): 8 stride-8 accumulators,
  // combined ((r0+r1)+(r2+r3))+((r4+r5)+(r6+r7)). float4 loads keep the
  // exact same per-accumulator add order; 32 loads instead of 128.
  const float4* zr4 = (const float4*)(z + b * ZD);
  const float4 pa = zr4[0], pb = zr4[1];
  float r0 = pa.x, r1 = pa.y, r2 = pa.z, r3 = pa.w;
  float r4 = pb.x, r5 = pb.y, r6 = pb.z, r7 = pb.w;
  #pragma unroll
  for (int i = 2; i < ZD / 4; i += 2) {
    const float4 a = zr4[i], d = zr4[i + 1];
    r0 += a.x; r1 += a.y; r2 += a.z; r3 += a.w;
    r4 += d.x; r5 += d.y; r6 += d.z; r7 += d.w;
  }
  float res = ((r0 + r1) + (r2 + r3)) + ((r4 + r5) + (r6 + r7));
  float v = fabsf(res) * 1000.0f;
  int cb = ((int)floorf(v)) & (N_LINEARS - 1);

  int pos = atomicAdd(&cnt[cb], 1);          // LDS atomic: fast, no XCD traffic
  lists[(cb << 9) + pos] = b;
  bp[b] = cb | (pos << 4);

  __syncthreads();
  if (b < N_LINEARS) counts[b] = cnt[b];
}

// ---------------- Kernel A2: z scatter into bucket-grouped k-major zgT ----
// zgT[c][k][slot]; 512 blocks (one per sample) x 128 threads (one per k).
__global__ __launch_bounds__(128) void gather_kernel(
    const float* __restrict__ z, const int* __restrict__ bp,
    float* __restrict__ zgT) {
  const int b = blockIdx.x;
  const int k = threadIdx.x;
  const int v = bp[b];
  const int cb = v & 15;
  const int pos = v >> 4;
  if (pos < SLOTS)
    zgT[(size_t)cb * (ZROWS * SLOTS) + (size_t)k * SLOTS + pos] = z[b * ZD + k];
}

// ---------------- Kernel B: grouped GEMM ----------------
// grid (48 j-tiles, 16 buckets) x 256 thr; thread owns column j, up to 48
// sample accumulators in NV x vf16 (NV adapted to tile population). z tile
// lives in LDS (ds_read broadcast, lgkmcnt) -> W's HBM prefetch keeps vmcnt
// to itself. z rows ping-pong through vf16 triples (SSA, no scratch).

#define ZL(N0, N1, N2, K1)                                           \
  { const vf16u* zr_ = (const vf16u*)(zp + (K1) * SLOTS);            \
    N0 = zr_[0];                                                     \
    if constexpr (NV >= 2) N1 = zr_[1];                              \
    if constexpr (NV >= 3) N2 = zr_[2]; }

#define ZF(C0, C1, C2, WK)                                           \
  { const float wk_ = (WK);                                          \
    vf16 wv_;                                                        \
    _Pragma("unroll") for (int e = 0; e < 16; ++e) wv_[e] = wk_;     \
    acc0 += C0 * wv_;                                                \
    if constexpr (NV >= 2) acc1 += C1 * wv_;                         \
    if constexpr (NV >= 3) acc2 += C2 * wv_; }

#define STEP(C0, C1, C2, N0, N1, N2, K1, WK)                         \
  ZL(N0, N1, N2, K1) ZF(C0, C1, C2, WK)

template <int NV>
__device__ __forceinline__ void tile_body(
    const float* __restrict__ zp,        // LDS: &zsh[s0]
    const float4* __restrict__ Wv, float bj,
    float* __restrict__ out, const int* lst, int m, int j) {
  vf16 acc0, acc1, acc2;
  _Pragma("unroll") for (int e = 0; e < 16; ++e) acc0[e] = bj;
  if constexpr (NV >= 2) {
    _Pragma("unroll") for (int e = 0; e < 16; ++e) acc1[e] = bj;
  }
  if constexpr (NV >= 3) {
    _Pragma("unroll") for (int e = 0; e < 16; ++e) acc2[e] = bj;
  }

  vf16 zA0, zA1, zA2, zB0, zB1, zB2;
  ZL(zA0, zA1, zA2, 0)
  float4 wq  = Wv[0];
  float4 wqn = Wv[1];

  for (int kc = 0; kc < ZD / 4; ++kc) {
    const int k0 = kc * 4;
    STEP(zA0, zA1, zA2, zB0, zB1, zB2, k0 + 1, wq.x)
    STEP(zB0, zB1, zB2, zA0, zA1, zA2, k0 + 2, wq.y)
    STEP(zA0, zA1, zA2, zB0, zB1, zB2, k0 + 3, wq.z)
    STEP(zB0, zB1, zB2, zA0, zA1, zA2, k0 + 4, wq.w)  // kc=31: pad row, unused
    wq = wqn;
    const int wi = kc + 2 > 31 ? 31 : kc + 2;
    wqn = Wv[wi];
  }

  _Pragma("unroll") for (int t = 0; t < 16; ++t)
    if (t < m) out[(size_t)lst[t] * BLOCK_OUT + j] = acc0[t];
  if constexpr (NV >= 2) {
    _Pragma("unroll") for (int t = 0; t < 16; ++t)
      if (16 + t < m) out[(size_t)lst[16 + t] * BLOCK_OUT + j] = acc1[t];
  }
  if constexpr (NV >= 3) {
    _Pragma("unroll") for (int t = 0; t < 16; ++t)
      if (32 + t < m) out[(size_t)lst[32 + t] * BLOCK_OUT + j] = acc2[t];
  }
}

__global__ __launch_bounds__(TJ, 3) void gen_main_kernel(
    const float* __restrict__ W, const float* __restrict__ bias,
    float* __restrict__ out, const int* __restrict__ counts,
    const int* __restrict__ lists, const float* __restrict__ zgT) {
  __shared__ float zsh[ZROWS * SLOTS];   // 33,024 B: z tile, [k][slot]
  __shared__ int   lsh[SLOTS];
  const int c = blockIdx.y;
  const int j = blockIdx.x * TJ + threadIdx.x;
  int n = counts[c];
  n = n > SLOTS ? SLOTS : n;
  if (n == 0) return;                    // uniform per block: safe before barrier

  {  // stage z tile (linear b128 copy, coalesced, conflict-free) + lists
    const float4* zg4 = (const float4*)(zgT + (size_t)c * (ZROWS * SLOTS));
    float4* ls4 = (float4*)zsh;
    #pragma unroll
    for (int i = 0; i < 9; ++i) {
      const int idx = threadIdx.x + i * TJ;
      if (idx < (ZROWS * SLOTS) / 4) ls4[idx] = zg4[idx];
    }
    if (threadIdx.x < SLOTS) lsh[threadIdx.x] = lists[(c << 9) + threadIdx.x];
  }
  __syncthreads();

  const size_t row = (size_t)c * BLOCK_OUT + (size_t)j;
  const float4* __restrict__ Wv = (const float4*)(W + row * (size_t)ZD);
  const float bj = bias[row];

  for (int s0 = 0; s0 < n; s0 += STILE) {
    const int mm = n - s0;
    const int m = mm > STILE ? STILE : mm;
    if (m <= 16)                         // uniform branch (n same across block)
      tile_body<1>(zsh + s0, Wv, bj, out, lsh + s0, m, j);
    else if (m <= 32)
      tile_body<2>(zsh + s0, Wv, bj, out, lsh + s0, m, j);
    else
      tile_body<3>(zsh + s0, Wv, bj, out, lsh + s0, m, j);
  }
}

extern "C" void kernel_launch(void* const* d_in, const int* in_sizes, int n_in,
                              void* d_out, int out_size, void* d_ws, size_t ws_size,
                              hipStream_t stream) {
  const float* z    = (const float*)d_in[0];   // 512*128
  const float* W    = (const float*)d_in[1];   // 196608*128
  const float* bias = (const float*)d_in[2];   // 196608
  float* out = (float*)d_out;                  // 512*12288

  int*   counts = (int*)d_ws;
  int*   lists  = (int*)d_ws + LISTS_OFF;
  int*   bp     = (int*)d_ws + BP_OFF;
  float* zgT    = (float*)((char*)d_ws + ZG_OFF_BYTES); // 16*129*64 floats

  hipLaunchKernelGGL(hash_kernel, dim3(1), dim3(BATCH), 0, stream,
                     z, counts, lists, bp);
  hipLaunchKernelGGL(gather_kernel, dim3(BATCH), dim3(ZD), 0, stream,
                     z, bp, zgT);

  dim3 grid(BLOCK_OUT / TJ, N_LINEARS);        // (48, 16)
  hipLaunchKernelGGL(gen_main_kernel, grid, dim3(TJ), 0, stream,
                     W, bias, out, counts, lists, zgT);
}